// Round 1
// baseline (368.112 us; speedup 1.0000x reference)
//
#include <hip/hip_runtime.h>

// ---------------------------------------------------------------------------
// self_transformer: q=xW1^T+b1, k=xW2^T+b2, v=xW3^T+b3,
//                   attn=softmax((k q^T)/sqrt(D)), out=attn@v
// N=4096, D_IN=D_OUT=1024. All matmuls via mfma_f32_16x16x32_bf16 (fp32 acc).
// ---------------------------------------------------------------------------

typedef short bf16x8 __attribute__((ext_vector_type(8)));  // 8 bf16 = 4 VGPRs
typedef float f32x4  __attribute__((ext_vector_type(4)));

__device__ __forceinline__ short f2bf(float f) {
    unsigned u = __builtin_bit_cast(unsigned, f);
    u += 0x7FFFu + ((u >> 16) & 1u);   // round-to-nearest-even
    return (short)(u >> 16);
}

#define BM 128
#define BN 128
#define BK 32
#define LDS_LD 40   // 32 + 8 pad: row stride 80 B -> worst 2-way bank alias (free)

// BT GEMM: C[a][b] = scale * sum_i A[a*lda+i] * B[b*ldb+i]  (+ bias)
// bias_mode: 0 none, 1 per-col (bias[b]), 2 per-row (bias[a])
// c_fp32: 1 -> float C, 0 -> bf16 C.  Requires M%128==0, N%128==0, K%32==0.
__global__ __launch_bounds__(256)
void gemm_bt(const short* __restrict__ A, int lda,
             const short* __restrict__ B, int ldb,
             const float* __restrict__ bias, int bias_mode,
             void* __restrict__ Cout, int ldc, int c_fp32, float scale,
             int K)
{
    __shared__ __align__(16) short As[BM * LDS_LD];
    __shared__ __align__(16) short Bs[BN * LDS_LD];

    const int tid  = threadIdx.x;
    const int lane = tid & 63;
    const int wave = tid >> 6;
    const int wm   = (wave >> 1) * 64;   // wave row offset in 128x128 tile
    const int wn   = (wave & 1) * 64;    // wave col offset
    const int quad = lane >> 4;
    const int l16  = lane & 15;
    const size_t bm0 = (size_t)blockIdx.y * BM;
    const size_t bn0 = (size_t)blockIdx.x * BN;

    f32x4 acc[4][4] = {};

    // staging assignment: 512 16-byte chunks (128 rows x 4 chunks) per matrix
    const int r0 = tid >> 2;         // 0..63
    const int c0 = (tid & 3) << 3;   // 0,8,16,24 (bf16 elems)

    for (int k0 = 0; k0 < K; k0 += BK) {
#pragma unroll
        for (int h = 0; h < 2; h++) {
            const int row = r0 + h * 64;
            const int4 va = *(const int4*)(A + (bm0 + row) * (size_t)lda + k0 + c0);
            const int4 vb = *(const int4*)(B + (bn0 + row) * (size_t)ldb + k0 + c0);
            *(int4*)(&As[row * LDS_LD + c0]) = va;
            *(int4*)(&Bs[row * LDS_LD + c0]) = vb;
        }
        __syncthreads();

        bf16x8 af[4], bfr[4];
#pragma unroll
        for (int mt = 0; mt < 4; mt++)
            af[mt] = *(const bf16x8*)(&As[(wm + mt * 16 + l16) * LDS_LD + quad * 8]);
#pragma unroll
        for (int nt = 0; nt < 4; nt++)
            bfr[nt] = *(const bf16x8*)(&Bs[(wn + nt * 16 + l16) * LDS_LD + quad * 8]);

#pragma unroll
        for (int mt = 0; mt < 4; mt++)
#pragma unroll
            for (int nt = 0; nt < 4; nt++)
                acc[mt][nt] = __builtin_amdgcn_mfma_f32_16x16x32_bf16(
                    af[mt], bfr[nt], acc[mt][nt], 0, 0, 0);
        __syncthreads();
    }

    // epilogue: C/D layout col=lane&15, row=quad*4+reg
#pragma unroll
    for (int mt = 0; mt < 4; mt++) {
#pragma unroll
        for (int nt = 0; nt < 4; nt++) {
            const size_t col = bn0 + wn + nt * 16 + l16;
            const float bcol = (bias_mode == 1) ? bias[col] : 0.0f;
#pragma unroll
            for (int r = 0; r < 4; r++) {
                const size_t row = bm0 + wm + mt * 16 + quad * 4 + r;
                float v = acc[mt][nt][r] * scale + bcol;
                if (bias_mode == 2) v += bias[row];
                if (c_fp32) ((float*)Cout)[row * (size_t)ldc + col] = v;
                else        ((short*)Cout)[row * (size_t)ldc + col] = f2bf(v);
            }
        }
    }
}

// Row softmax over 4096 cols; writes bf16 P in-place into the fp32 row's
// storage (P row n at byte offset n*16384, i.e. ldP = 8192 bf16 elems).
__global__ __launch_bounds__(256)
void softmax_rows(float* __restrict__ S)
{
    const int row = blockIdx.x;
    float* s = S + (size_t)row * 4096;
    short* p = (short*)s;            // same bytes; safe: all reads precede writes
    const int tid = threadIdx.x;
    const int wave = tid >> 6, lane = tid & 63;

    float v[16];
    float mx = -1e30f;
#pragma unroll
    for (int i = 0; i < 16; i++) {
        v[i] = s[tid + (i << 8)];
        mx = fmaxf(mx, v[i]);
    }
#pragma unroll
    for (int off = 32; off; off >>= 1) mx = fmaxf(mx, __shfl_down(mx, off));
    __shared__ float red[4];
    if (lane == 0) red[wave] = mx;
    __syncthreads();
    mx = fmaxf(fmaxf(red[0], red[1]), fmaxf(red[2], red[3]));

    float sum = 0.0f;
#pragma unroll
    for (int i = 0; i < 16; i++) { v[i] = __expf(v[i] - mx); sum += v[i]; }
#pragma unroll
    for (int off = 32; off; off >>= 1) sum += __shfl_down(sum, off);
    __syncthreads();                 // red reuse guard
    if (lane == 0) red[wave] = sum;
    __syncthreads();
    sum = red[0] + red[1] + red[2] + red[3];
    const float inv = 1.0f / sum;

#pragma unroll
    for (int i = 0; i < 16; i++) p[tid + (i << 8)] = f2bf(v[i] * inv);
}

__global__ __launch_bounds__(256)
void cast4(const float* __restrict__ in, short* __restrict__ out, int n4)
{
    const int i = blockIdx.x * 256 + threadIdx.x;
    if (i >= n4) return;
    const float4 f = ((const float4*)in)[i];
    short4 o;
    o.x = f2bf(f.x); o.y = f2bf(f.y); o.z = f2bf(f.z); o.w = f2bf(f.w);
    ((short4*)out)[i] = o;
}

extern "C" void kernel_launch(void* const* d_in, const int* in_sizes, int n_in,
                              void* d_out, int out_size, void* d_ws, size_t ws_size,
                              hipStream_t stream)
{
    const float* x  = (const float*)d_in[0];
    const float* W1 = (const float*)d_in[1];
    const float* b1 = (const float*)d_in[2];
    const float* W2 = (const float*)d_in[3];
    const float* b2 = (const float*)d_in[4];
    const float* W3 = (const float*)d_in[5];
    const float* b3 = (const float*)d_in[6];
    float* out = (float*)d_out;

    const int N = 4096, D = 1024;

    // workspace layout (102 MB total)
    short* xb  = (short*)d_ws;                 // 4096x1024 bf16  (8 MB)
    short* W1b = xb  + (size_t)N * D;          // 1024x1024 bf16  (2 MB)
    short* W2b = W1b + (size_t)D * D;
    short* W3b = W2b + (size_t)D * D;
    short* qb  = W3b + (size_t)D * D;          // 4096x1024 bf16  (8 MB)
    short* kb  = qb  + (size_t)N * D;          // 4096x1024 bf16
    short* vt  = kb  + (size_t)N * D;          // 1024x4096 bf16 (V transposed)
    float* S   = (float*)(vt + (size_t)N * D); // 4096x4096 fp32 (64 MB); P aliases

    // 1) casts to bf16
    cast4<<<(N * D / 4) / 256, 256, 0, stream>>>(x,  xb,  N * D / 4);
    cast4<<<(D * D / 4) / 256, 256, 0, stream>>>(W1, W1b, D * D / 4);
    cast4<<<(D * D / 4) / 256, 256, 0, stream>>>(W2, W2b, D * D / 4);
    cast4<<<(D * D / 4) / 256, 256, 0, stream>>>(W3, W3b, D * D / 4);

    // 2) projections
    dim3 gqk(D / BN, N / BM);   // (8, 32)
    gemm_bt<<<gqk, 256, 0, stream>>>(xb, D, W1b, D, b1, 1, qb, D, 0, 1.0f, D);
    gemm_bt<<<gqk, 256, 0, stream>>>(xb, D, W2b, D, b2, 1, kb, D, 0, 1.0f, D);
    // v^T[d][n] = sum_i W3[d,i] x[n,i] + b3[d]  (bias per row)
    dim3 gvt(N / BN, D / BM);   // (32, 8)
    gemm_bt<<<gvt, 256, 0, stream>>>(W3b, D, xb, D, b3, 2, vt, N, 0, 1.0f, D);

    // 3) S = (k q^T) / sqrt(D)  -> fp32
    dim3 gs(N / BN, N / BM);    // (32, 32)
    gemm_bt<<<gs, 256, 0, stream>>>(kb, D, qb, D, nullptr, 0, S, N, 1, 0.03125f, D);

    // 4) softmax rows -> bf16 P in-place (ldP = 8192)
    softmax_rows<<<N, 256, 0, stream>>>(S);

    // 5) out[n][d] = sum_m P[n,m] v^T[d,m]
    dim3 go(D / BN, N / BM);    // (8, 32)
    gemm_bt<<<go, 256, 0, stream>>>((const short*)S, 2 * N, vt, N,
                                    nullptr, 0, out, D, 1, 1.0f, N);
}

// Round 2
// 297.211 us; speedup vs baseline: 1.2386x; 1.2386x over previous
//
#include <hip/hip_runtime.h>

// ---------------------------------------------------------------------------
// self_transformer: q=xW1^T+b1, k=xW2^T+b2, v=xW3^T+b3,
//                   attn=softmax((k q^T)/sqrt(D)), out=attn@v
// N=4096, D=1024. All matmuls via mfma_f32_16x16x32_bf16, fp32 accum.
// R2: global_load_lds width-16 staging (m97 pattern), merged q|k projection,
//     128x64 tiles for the skinny gemms -> >=512 blocks (2 blocks/CU) on
//     every GEMM dispatch.
// ---------------------------------------------------------------------------

typedef short bf16x8 __attribute__((ext_vector_type(8)));  // 8 bf16 = 4 VGPRs
typedef float f32x4  __attribute__((ext_vector_type(4)));

__device__ __forceinline__ short f2bf(float f) {
    unsigned u = __builtin_bit_cast(unsigned, f);
    u += 0x7FFFu + ((u >> 16) & 1u);   // round-to-nearest-even
    return (short)(u >> 16);
}

__device__ __forceinline__ void gld_lds16(const short* g, short* l) {
    __builtin_amdgcn_global_load_lds(
        (const __attribute__((address_space(1))) void*)g,
        (__attribute__((address_space(3))) void*)l, 16, 0, 0);
}

// BT GEMM: C[a][b] = scale * sum_i A[a*lda+i] * B[b*ldb+i]  (+ bias)
// bias_mode: 0 none, 1 per-col bias[b], 2 per-row bias[a]
// c_fp32: 1 -> float C, 0 -> bf16 C.  M%BM==0, N%BN==0, K%32==0.
// LDS layout: unpadded [rows][32] bf16 rows of 64 B — required by the
// global_load_lds wave-uniform-base+lane*16 contract. ds_read_b128 fragment
// reads are bank-balanced (8 accesses/bank) at this stride.
template<int BM, int BN>
__global__ __launch_bounds__(256)
void gemm_bt(const short* __restrict__ A, int lda,
             const short* __restrict__ B, int ldb,
             const float* __restrict__ bias, int bias_mode,
             void* __restrict__ Cout, int ldc, int c_fp32, float scale,
             int K)
{
    constexpr int NT = BN / 32;                 // MFMA col-tiles per wave
    __shared__ __align__(16) short As[BM * 32];
    __shared__ __align__(16) short Bs[BN * 32];

    const int tid  = threadIdx.x;
    const int lane = tid & 63;
    const int wave = tid >> 6;
    const int wm   = (wave >> 1) * 64;          // wave row offset
    const int wn   = (wave & 1) * (BN / 2);     // wave col offset
    const int quad = lane >> 4;
    const int l16  = lane & 15;
    const size_t bm0 = (size_t)blockIdx.y * BM;
    const size_t bn0 = (size_t)blockIdx.x * BN;

    f32x4 acc[4][NT] = {};

    // staging: lane i of a chunk-instruction covers row chunk*16 + (i>>2),
    // k-chunk (i&3)*8 elems -> lands at LDS base + i*16 B (contract).
    const int srow = lane >> 2;
    const int scol = (lane & 3) << 3;
    const short* Ag = A + (bm0 + srow) * (size_t)lda + scol;
    const short* Bg = B + (bn0 + srow) * (size_t)ldb + scol;

    for (int k0 = 0; k0 < K; k0 += 32) {
#pragma unroll
        for (int c = 0; c < BM / 16; c += 4)
            gld_lds16(Ag + (size_t)(c + wave) * 16 * lda + k0,
                      &As[(c + wave) * 512]);
#pragma unroll
        for (int c = 0; c < BN / 16; c += 4)
            gld_lds16(Bg + (size_t)(c + wave) * 16 * ldb + k0,
                      &Bs[(c + wave) * 512]);
        __syncthreads();

        bf16x8 af[4], bfr[NT];
#pragma unroll
        for (int mt = 0; mt < 4; mt++)
            af[mt] = *(const bf16x8*)(&As[(wm + mt * 16 + l16) * 32 + quad * 8]);
#pragma unroll
        for (int nt = 0; nt < NT; nt++)
            bfr[nt] = *(const bf16x8*)(&Bs[(wn + nt * 16 + l16) * 32 + quad * 8]);

#pragma unroll
        for (int mt = 0; mt < 4; mt++)
#pragma unroll
            for (int nt = 0; nt < NT; nt++)
                acc[mt][nt] = __builtin_amdgcn_mfma_f32_16x16x32_bf16(
                    af[mt], bfr[nt], acc[mt][nt], 0, 0, 0);
        __syncthreads();
    }

    // epilogue: C/D layout col=lane&15, row=quad*4+reg
#pragma unroll
    for (int mt = 0; mt < 4; mt++) {
#pragma unroll
        for (int nt = 0; nt < NT; nt++) {
            const size_t col = bn0 + wn + nt * 16 + l16;
            const float bcol = (bias_mode == 1) ? bias[col] : 0.0f;
#pragma unroll
            for (int r = 0; r < 4; r++) {
                const size_t row = bm0 + wm + mt * 16 + quad * 4 + r;
                float v = acc[mt][nt][r] * scale + bcol;
                if (bias_mode == 2) v += bias[row];
                if (c_fp32) ((float*)Cout)[row * (size_t)ldc + col] = v;
                else        ((short*)Cout)[row * (size_t)ldc + col] = f2bf(v);
            }
        }
    }
}

// Row softmax over 4096 fp32 cols; writes bf16 P in-place into the fp32 row's
// storage (ldP = 8192 bf16). Safe: all global reads complete before the
// reduction __syncthreads barriers, all writes after.
__global__ __launch_bounds__(256)
void softmax_rows(float* __restrict__ S)
{
    const int row = blockIdx.x;
    float* s = S + (size_t)row * 4096;
    short* p = (short*)s;
    const int tid = threadIdx.x;
    const int wave = tid >> 6, lane = tid & 63;

    float v[16];
    float mx = -1e30f;
#pragma unroll
    for (int i = 0; i < 16; i++) {
        v[i] = s[tid + (i << 8)];
        mx = fmaxf(mx, v[i]);
    }
#pragma unroll
    for (int off = 32; off; off >>= 1) mx = fmaxf(mx, __shfl_down(mx, off));
    __shared__ float red[4];
    if (lane == 0) red[wave] = mx;
    __syncthreads();
    mx = fmaxf(fmaxf(red[0], red[1]), fmaxf(red[2], red[3]));

    float sum = 0.0f;
#pragma unroll
    for (int i = 0; i < 16; i++) { v[i] = __expf(v[i] - mx); sum += v[i]; }
#pragma unroll
    for (int off = 32; off; off >>= 1) sum += __shfl_down(sum, off);
    __syncthreads();
    if (lane == 0) red[wave] = sum;
    __syncthreads();
    sum = red[0] + red[1] + red[2] + red[3];
    const float inv = 1.0f / sum;

#pragma unroll
    for (int i = 0; i < 16; i++) p[tid + (i << 8)] = f2bf(v[i] * inv);
}

__global__ __launch_bounds__(256)
void cast4(const float* __restrict__ in, short* __restrict__ out, int n4)
{
    const int i = blockIdx.x * 256 + threadIdx.x;
    if (i >= n4) return;
    const float4 f = ((const float4*)in)[i];
    short4 o;
    o.x = f2bf(f.x); o.y = f2bf(f.y); o.z = f2bf(f.z); o.w = f2bf(f.w);
    ((short4*)out)[i] = o;
}

// cast W1,W2,W3 (each per4 float4's) into one contiguous bf16 [3*D x D]
__global__ __launch_bounds__(256)
void cast_w3(const float* __restrict__ W1, const float* __restrict__ W2,
             const float* __restrict__ W3, short* __restrict__ out, int per4)
{
    const int i = blockIdx.x * 256 + threadIdx.x;
    if (i >= 3 * per4) return;
    const float* src = (i < per4) ? W1 : (i < 2 * per4 ? W2 : W3);
    const int j = (i < per4) ? i : (i < 2 * per4 ? i - per4 : i - 2 * per4);
    const float4 f = ((const float4*)src)[j];
    short4 o;
    o.x = f2bf(f.x); o.y = f2bf(f.y); o.z = f2bf(f.z); o.w = f2bf(f.w);
    ((short4*)out)[i] = o;
}

__global__ __launch_bounds__(256)
void bias_cat2(const float* __restrict__ b1, const float* __restrict__ b2,
               float* __restrict__ cat, int n)
{
    const int i = blockIdx.x * 256 + threadIdx.x;
    if (i < n) cat[i] = b1[i];
    else if (i < 2 * n) cat[i] = b2[i - n];
}

extern "C" void kernel_launch(void* const* d_in, const int* in_sizes, int n_in,
                              void* d_out, int out_size, void* d_ws, size_t ws_size,
                              hipStream_t stream)
{
    const float* x  = (const float*)d_in[0];
    const float* W1 = (const float*)d_in[1];
    const float* b1 = (const float*)d_in[2];
    const float* W2 = (const float*)d_in[3];
    const float* b2 = (const float*)d_in[4];
    const float* W3 = (const float*)d_in[5];
    const float* b3 = (const float*)d_in[6];
    float* out = (float*)d_out;

    const int N = 4096, D = 1024;

    // workspace (~102 MB)
    short* xb   = (short*)d_ws;                  // 4096x1024 bf16 (8 MB)
    short* Wb   = xb + (size_t)N * D;            // [W1;W2;W3] 3072x1024 (6 MB)
    float* bcat = (float*)(Wb + (size_t)3 * D * D); // 2048 fp32
    short* qk   = (short*)(bcat + 2 * D);        // 4096x2048 bf16 (16 MB)
    short* vt   = qk + (size_t)N * 2 * D;        // 1024x4096 bf16 (8 MB)
    float* S    = (float*)(vt + (size_t)N * D);  // 4096x4096 fp32 (64 MB); P aliases

    // 1) casts
    cast4<<<(N * D / 4) / 256, 256, 0, stream>>>(x, xb, N * D / 4);
    cast_w3<<<(3 * D * D / 4) / 256, 256, 0, stream>>>(W1, W2, W3, Wb, D * D / 4);
    bias_cat2<<<(2 * D + 255) / 256, 256, 0, stream>>>(b1, b2, bcat, D);

    // 2) qk = x @ [W1;W2]^T + [b1;b2]   grid (16,32)=512 blocks
    dim3 gqk(2 * D / 128, N / 128);
    gemm_bt<128, 128><<<gqk, 256, 0, stream>>>(xb, D, Wb, D, bcat, 1,
                                               qk, 2 * D, 0, 1.0f, D);

    // 3) v^T[d][n] = W3[d]·x[n] + b3[d]  grid (64,8)=512 blocks
    dim3 gvt(N / 64, D / 128);
    gemm_bt<128, 64><<<gvt, 256, 0, stream>>>(Wb + (size_t)2 * D * D, D, xb, D,
                                              b3, 2, vt, N, 0, 1.0f, D);

    // 4) S = (k q^T)/32  -> fp32   grid (32,32)=1024 blocks
    dim3 gs(N / 128, N / 128);
    gemm_bt<128, 128><<<gs, 256, 0, stream>>>(qk + D, 2 * D, qk, 2 * D,
                                              nullptr, 0, S, N, 1, 0.03125f, D);

    // 5) softmax rows -> bf16 P in place (ldP = 8192)
    softmax_rows<<<N, 256, 0, stream>>>(S);

    // 6) out[n][d] = sum_m P[n,m] v^T[d,m]  grid (16,32)=512 blocks
    dim3 go(D / 64, N / 128);
    gemm_bt<128, 64><<<go, 256, 0, stream>>>((const short*)S, 2 * N, vt, N,
                                             nullptr, 0, out, D, 1, 1.0f, N);
}

// Round 3
// 264.623 us; speedup vs baseline: 1.3911x; 1.1231x over previous
//
#include <hip/hip_runtime.h>

// ---------------------------------------------------------------------------
// self_transformer: q=xW1^T+b1, k=xW2^T+b2, v=xW3^T+b3,
//                   attn=softmax((k q^T)/sqrt(D)), out=attn@v
// N=4096, D=1024. All matmuls via mfma_f32_16x16x32_bf16, fp32 accum.
// R3: BK=64 (2x MFMA per barrier-drain), XOR-swizzled LDS granules
//     (2-way bank alias = free, vs 16-way naive at 128B row stride),
//     bf16 S (halves S-write + softmax-read traffic).
// ---------------------------------------------------------------------------

typedef short bf16x8 __attribute__((ext_vector_type(8)));  // 8 bf16 = 4 VGPRs
typedef float f32x4  __attribute__((ext_vector_type(4)));

__device__ __forceinline__ short f2bf(float f) {
    unsigned u = __builtin_bit_cast(unsigned, f);
    u += 0x7FFFu + ((u >> 16) & 1u);   // round-to-nearest-even
    return (short)(u >> 16);
}
__device__ __forceinline__ float bf2f(short s) {
    return __builtin_bit_cast(float, (unsigned)((unsigned short)s) << 16);
}

__device__ __forceinline__ void gld_lds16(const short* g, short* l) {
    __builtin_amdgcn_global_load_lds(
        (const __attribute__((address_space(1))) void*)g,
        (__attribute__((address_space(3))) void*)l, 16, 0, 0);
}

// BT GEMM: C[a][b] = scale * sum_i A[a*lda+i] * B[b*ldb+i]  (+ bias)
// bias_mode: 0 none, 1 per-col bias[b], 2 per-row bias[a]
// c_fp32: 1 -> float C, 0 -> bf16 C.  M%BM==0, N%BN==0, K%64==0.
//
// LDS: BK=64 -> row = 8 x 16B granules (128 B). A stage chunk = 8 rows
// (1024 B). Lane i of a chunk lands at LDS base+i*16 (HW contract), i.e.
// row i>>3, LDS granule i&7; we LOAD global granule (i&7)^(i>>3) so that
// LDS granule p of row r holds global granule p^(r&7). Fragment read for
// k-step ks then hits LDS granule (ks*4+quad)^(r&7): for 16 lanes (l16
// 0..15, fixed quad) that's every granule group twice -> 2-way = free.
template<int BM, int BN>
__global__ __launch_bounds__(256)
void gemm_bt(const short* __restrict__ A, int lda,
             const short* __restrict__ B, int ldb,
             const float* __restrict__ bias, int bias_mode,
             void* __restrict__ Cout, int ldc, int c_fp32, float scale,
             int K)
{
    constexpr int NT = BN / 32;                 // MFMA col-tiles per wave
    __shared__ __align__(16) short As[BM * 64];
    __shared__ __align__(16) short Bs[BN * 64];

    const int tid  = threadIdx.x;
    const int lane = tid & 63;
    const int wave = tid >> 6;
    const int wm   = (wave >> 1) * 64;          // wave row offset
    const int wn   = (wave & 1) * (BN / 2);     // wave col offset
    const int quad = lane >> 4;
    const int l16  = lane & 15;
    const size_t bm0 = (size_t)blockIdx.y * BM;
    const size_t bn0 = (size_t)blockIdx.x * BN;

    f32x4 acc[4][NT] = {};

    // staging lane decode: chunk row + swizzled global granule
    const int srow = lane >> 3;                        // 0..7
    const int scol = ((lane & 7) ^ srow) << 3;         // swizzled elem col
    const short* Ag = A + (bm0 + srow) * (size_t)lda + scol;
    const short* Bg = B + (bn0 + srow) * (size_t)ldb + scol;

    for (int k0 = 0; k0 < K; k0 += 64) {
#pragma unroll
        for (int cc = 0; cc < BM / 8; cc += 4) {
            const int c = cc + wave;
            gld_lds16(Ag + (size_t)c * 8 * lda + k0, &As[c * 512]);
        }
#pragma unroll
        for (int cc = 0; cc < BN / 8; cc += 4) {
            const int c = cc + wave;
            gld_lds16(Bg + (size_t)c * 8 * ldb + k0, &Bs[c * 512]);
        }
        __syncthreads();

        bf16x8 af[2][4], bfr[2][NT];
#pragma unroll
        for (int ks = 0; ks < 2; ks++) {
            const int sw = (ks << 2) + quad;
#pragma unroll
            for (int mt = 0; mt < 4; mt++) {
                const int r = wm + mt * 16 + l16;
                af[ks][mt] = *(const bf16x8*)(&As[r * 64 + ((sw ^ (r & 7)) << 3)]);
            }
#pragma unroll
            for (int nt = 0; nt < NT; nt++) {
                const int r = wn + nt * 16 + l16;
                bfr[ks][nt] = *(const bf16x8*)(&Bs[r * 64 + ((sw ^ (r & 7)) << 3)]);
            }
        }
#pragma unroll
        for (int ks = 0; ks < 2; ks++)
#pragma unroll
            for (int mt = 0; mt < 4; mt++)
#pragma unroll
                for (int nt = 0; nt < NT; nt++)
                    acc[mt][nt] = __builtin_amdgcn_mfma_f32_16x16x32_bf16(
                        af[ks][mt], bfr[ks][nt], acc[mt][nt], 0, 0, 0);
        __syncthreads();
    }

    // epilogue: C/D layout col=lane&15, row=quad*4+reg
#pragma unroll
    for (int mt = 0; mt < 4; mt++) {
#pragma unroll
        for (int nt = 0; nt < NT; nt++) {
            const size_t col = bn0 + wn + nt * 16 + l16;
            const float bcol = (bias_mode == 1) ? bias[col] : 0.0f;
#pragma unroll
            for (int r = 0; r < 4; r++) {
                const size_t row = bm0 + wm + mt * 16 + quad * 4 + r;
                float v = acc[mt][nt][r] * scale + bcol;
                if (bias_mode == 2) v += bias[row];
                if (c_fp32) ((float*)Cout)[row * (size_t)ldc + col] = v;
                else        ((short*)Cout)[row * (size_t)ldc + col] = f2bf(v);
            }
        }
    }
}

// Row softmax over 4096 bf16 cols, in place (dense ld=4096).
// Each thread owns 16 contiguous elems; fp32 math internally.
__global__ __launch_bounds__(256)
void softmax_rows_bf16(short* __restrict__ P)
{
    short* p = P + (size_t)blockIdx.x * 4096;
    const int tid = threadIdx.x;
    const int wave = tid >> 6, lane = tid & 63;
    const int base = tid << 4;

    short sh[16];
    *(int4*)(sh)     = *(const int4*)(p + base);
    *(int4*)(sh + 8) = *(const int4*)(p + base + 8);

    float v[16];
    float mx = -1e30f;
#pragma unroll
    for (int i = 0; i < 16; i++) { v[i] = bf2f(sh[i]); mx = fmaxf(mx, v[i]); }
#pragma unroll
    for (int off = 32; off; off >>= 1) mx = fmaxf(mx, __shfl_down(mx, off));
    __shared__ float red[4];
    if (lane == 0) red[wave] = mx;
    __syncthreads();
    mx = fmaxf(fmaxf(red[0], red[1]), fmaxf(red[2], red[3]));

    float sum = 0.0f;
#pragma unroll
    for (int i = 0; i < 16; i++) { v[i] = __expf(v[i] - mx); sum += v[i]; }
#pragma unroll
    for (int off = 32; off; off >>= 1) sum += __shfl_down(sum, off);
    __syncthreads();
    if (lane == 0) red[wave] = sum;
    __syncthreads();
    const float inv = 1.0f / (red[0] + red[1] + red[2] + red[3]);

#pragma unroll
    for (int i = 0; i < 16; i++) sh[i] = f2bf(v[i] * inv);
    *(int4*)(p + base)     = *(const int4*)(sh);
    *(int4*)(p + base + 8) = *(const int4*)(sh + 8);
}

__global__ __launch_bounds__(256)
void cast4(const float* __restrict__ in, short* __restrict__ out, int n4)
{
    const int i = blockIdx.x * 256 + threadIdx.x;
    if (i >= n4) return;
    const float4 f = ((const float4*)in)[i];
    short4 o;
    o.x = f2bf(f.x); o.y = f2bf(f.y); o.z = f2bf(f.z); o.w = f2bf(f.w);
    ((short4*)out)[i] = o;
}

__global__ __launch_bounds__(256)
void cast_w3(const float* __restrict__ W1, const float* __restrict__ W2,
             const float* __restrict__ W3, short* __restrict__ out, int per4)
{
    const int i = blockIdx.x * 256 + threadIdx.x;
    if (i >= 3 * per4) return;
    const float* src = (i < per4) ? W1 : (i < 2 * per4 ? W2 : W3);
    const int j = (i < per4) ? i : (i < 2 * per4 ? i - per4 : i - 2 * per4);
    const float4 f = ((const float4*)src)[j];
    short4 o;
    o.x = f2bf(f.x); o.y = f2bf(f.y); o.z = f2bf(f.z); o.w = f2bf(f.w);
    ((short4*)out)[i] = o;
}

__global__ __launch_bounds__(256)
void bias_cat2(const float* __restrict__ b1, const float* __restrict__ b2,
               float* __restrict__ cat, int n)
{
    const int i = blockIdx.x * 256 + threadIdx.x;
    if (i < n) cat[i] = b1[i];
    else if (i < 2 * n) cat[i] = b2[i - n];
}

extern "C" void kernel_launch(void* const* d_in, const int* in_sizes, int n_in,
                              void* d_out, int out_size, void* d_ws, size_t ws_size,
                              hipStream_t stream)
{
    const float* x  = (const float*)d_in[0];
    const float* W1 = (const float*)d_in[1];
    const float* b1 = (const float*)d_in[2];
    const float* W2 = (const float*)d_in[3];
    const float* b2 = (const float*)d_in[4];
    const float* W3 = (const float*)d_in[5];
    const float* b3 = (const float*)d_in[6];
    float* out = (float*)d_out;

    const int N = 4096, D = 1024;

    // workspace (~70 MB)
    short* xb   = (short*)d_ws;                     // 4096x1024 bf16 (8 MB)
    short* Wb   = xb + (size_t)N * D;               // [W1;W2;W3] 3072x1024 (6 MB)
    float* bcat = (float*)(Wb + (size_t)3 * D * D); // 2048 fp32
    short* qk   = (short*)(bcat + 2 * D);           // 4096x2048 bf16 (16 MB)
    short* vt   = qk + (size_t)N * 2 * D;           // 1024x4096 bf16 (8 MB)
    short* S    = vt + (size_t)N * D;               // 4096x4096 bf16 (32 MB)

    // 1) casts
    cast4<<<(N * D / 4) / 256, 256, 0, stream>>>(x, xb, N * D / 4);
    cast_w3<<<(3 * D * D / 4) / 256, 256, 0, stream>>>(W1, W2, W3, Wb, D * D / 4);
    bias_cat2<<<(2 * D + 255) / 256, 256, 0, stream>>>(b1, b2, bcat, D);

    // 2) qk = x @ [W1;W2]^T + [b1;b2]   grid (16,32)=512 blocks
    dim3 gqk(2 * D / 128, N / 128);
    gemm_bt<128, 128><<<gqk, 256, 0, stream>>>(xb, D, Wb, D, bcat, 1,
                                               qk, 2 * D, 0, 1.0f, D);

    // 3) v^T[d][n] = W3[d]·x[n] + b3[d]  grid (64,8)=512 blocks
    dim3 gvt(N / 64, D / 128);
    gemm_bt<128, 64><<<gvt, 256, 0, stream>>>(Wb + (size_t)2 * D * D, D, xb, D,
                                              b3, 2, vt, N, 0, 1.0f, D);

    // 4) S = (k q^T)/32 -> bf16   grid (32,32)=1024 blocks
    dim3 gs(N / 128, N / 128);
    gemm_bt<128, 128><<<gs, 256, 0, stream>>>(qk + D, 2 * D, qk, 2 * D,
                                              nullptr, 0, S, N, 0, 0.03125f, D);

    // 5) softmax rows, in place (bf16, dense ld=4096)
    softmax_rows_bf16<<<N, 256, 0, stream>>>(S);

    // 6) out[n][d] = sum_m P[n,m] v^T[d,m]  grid (16,32)=512 blocks
    dim3 go(D / 64, N / 128);
    gemm_bt<128, 64><<<go, 256, 0, stream>>>(S, N, vt, N,
                                             nullptr, 0, out, D, 1, 1.0f, N);
}

// Round 4
// 259.515 us; speedup vs baseline: 1.4185x; 1.0197x over previous
//
#include <hip/hip_runtime.h>

// ---------------------------------------------------------------------------
// self_transformer: q=xW1^T+b1, k=xW2^T+b2, v=xW3^T+b3,
//                   attn=softmax((k q^T)/sqrt(D)), out=attn@v
// N=4096, D=1024. All matmuls via mfma_f32_16x16x32_bf16, fp32 accum.
// R4: split-K=2 out-gemm (4 blocks/CU) + reduce; merged qkv projection
//     (one gemm, 3 blocks/CU) + LDS transpose for v^T.
// ---------------------------------------------------------------------------

typedef short bf16x8 __attribute__((ext_vector_type(8)));  // 8 bf16 = 4 VGPRs
typedef float f32x4  __attribute__((ext_vector_type(4)));

__device__ __forceinline__ short f2bf(float f) {
    unsigned u = __builtin_bit_cast(unsigned, f);
    u += 0x7FFFu + ((u >> 16) & 1u);   // round-to-nearest-even
    return (short)(u >> 16);
}
__device__ __forceinline__ float bf2f(short s) {
    return __builtin_bit_cast(float, (unsigned)((unsigned short)s) << 16);
}

__device__ __forceinline__ void gld_lds16(const short* g, short* l) {
    __builtin_amdgcn_global_load_lds(
        (const __attribute__((address_space(1))) void*)g,
        (__attribute__((address_space(3))) void*)l, 16, 0, 0);
}

// BT GEMM: C[a][b] = scale * sum_i A[a*lda+i] * B[b*ldb+i]  (+ bias)
// K = per-split depth; blockIdx.z selects split (A/B k-offset z*K, C offset
// z*zstride elements). bias_mode: 0 none, 1 per-col, 2 per-row.
// LDS: BK=64, XOR-swizzled 16B granules (see R3 comment) — conflict-free.
template<int BM, int BN>
__global__ __launch_bounds__(256)
void gemm_bt(const short* __restrict__ A, int lda,
             const short* __restrict__ B, int ldb,
             const float* __restrict__ bias, int bias_mode,
             void* __restrict__ Cout, int ldc, int c_fp32, float scale,
             int K, size_t zstride)
{
    constexpr int NT = BN / 32;                 // MFMA col-tiles per wave
    __shared__ __align__(16) short As[BM * 64];
    __shared__ __align__(16) short Bs[BN * 64];

    const int tid  = threadIdx.x;
    const int lane = tid & 63;
    const int wave = tid >> 6;
    const int wm   = (wave >> 1) * 64;          // wave row offset
    const int wn   = (wave & 1) * (BN / 2);     // wave col offset
    const int quad = lane >> 4;
    const int l16  = lane & 15;
    const size_t bm0 = (size_t)blockIdx.y * BM;
    const size_t bn0 = (size_t)blockIdx.x * BN;
    const int koff = blockIdx.z * K;

    f32x4 acc[4][NT] = {};

    // staging lane decode: chunk row + swizzled global granule
    const int srow = lane >> 3;                        // 0..7
    const int scol = ((lane & 7) ^ srow) << 3;         // swizzled elem col
    const short* Ag = A + (bm0 + srow) * (size_t)lda + koff + scol;
    const short* Bg = B + (bn0 + srow) * (size_t)ldb + koff + scol;

    for (int k0 = 0; k0 < K; k0 += 64) {
#pragma unroll
        for (int cc = 0; cc < BM / 8; cc += 4) {
            const int c = cc + wave;
            gld_lds16(Ag + (size_t)c * 8 * lda + k0, &As[c * 512]);
        }
#pragma unroll
        for (int cc = 0; cc < BN / 8; cc += 4) {
            const int c = cc + wave;
            gld_lds16(Bg + (size_t)c * 8 * ldb + k0, &Bs[c * 512]);
        }
        __syncthreads();

        bf16x8 af[2][4], bfr[2][NT];
#pragma unroll
        for (int ks = 0; ks < 2; ks++) {
            const int sw = (ks << 2) + quad;
#pragma unroll
            for (int mt = 0; mt < 4; mt++) {
                const int r = wm + mt * 16 + l16;
                af[ks][mt] = *(const bf16x8*)(&As[r * 64 + ((sw ^ (r & 7)) << 3)]);
            }
#pragma unroll
            for (int nt = 0; nt < NT; nt++) {
                const int r = wn + nt * 16 + l16;
                bfr[ks][nt] = *(const bf16x8*)(&Bs[r * 64 + ((sw ^ (r & 7)) << 3)]);
            }
        }
#pragma unroll
        for (int ks = 0; ks < 2; ks++)
#pragma unroll
            for (int mt = 0; mt < 4; mt++)
#pragma unroll
                for (int nt = 0; nt < NT; nt++)
                    acc[mt][nt] = __builtin_amdgcn_mfma_f32_16x16x32_bf16(
                        af[ks][mt], bfr[ks][nt], acc[mt][nt], 0, 0, 0);
        __syncthreads();
    }

    // epilogue: C/D layout col=lane&15, row=quad*4+reg
    float* Cf = (float*)Cout + blockIdx.z * zstride;
    short* Cs = (short*)Cout + blockIdx.z * zstride;
#pragma unroll
    for (int mt = 0; mt < 4; mt++) {
#pragma unroll
        for (int nt = 0; nt < NT; nt++) {
            const size_t col = bn0 + wn + nt * 16 + l16;
            const float bcol = (bias_mode == 1) ? bias[col] : 0.0f;
#pragma unroll
            for (int r = 0; r < 4; r++) {
                const size_t row = bm0 + wm + mt * 16 + quad * 4 + r;
                float v = acc[mt][nt][r] * scale + bcol;
                if (bias_mode == 2) v += bias[row];
                if (c_fp32) Cf[row * (size_t)ldc + col] = v;
                else        Cs[row * (size_t)ldc + col] = f2bf(v);
            }
        }
    }
}

// Row softmax over 4096 bf16 cols, in place (dense ld=4096), fp32 math.
__global__ __launch_bounds__(256)
void softmax_rows_bf16(short* __restrict__ P)
{
    short* p = P + (size_t)blockIdx.x * 4096;
    const int tid = threadIdx.x;
    const int wave = tid >> 6, lane = tid & 63;
    const int base = tid << 4;

    short sh[16];
    *(int4*)(sh)     = *(const int4*)(p + base);
    *(int4*)(sh + 8) = *(const int4*)(p + base + 8);

    float v[16];
    float mx = -1e30f;
#pragma unroll
    for (int i = 0; i < 16; i++) { v[i] = bf2f(sh[i]); mx = fmaxf(mx, v[i]); }
#pragma unroll
    for (int off = 32; off; off >>= 1) mx = fmaxf(mx, __shfl_down(mx, off));
    __shared__ float red[4];
    if (lane == 0) red[wave] = mx;
    __syncthreads();
    mx = fmaxf(fmaxf(red[0], red[1]), fmaxf(red[2], red[3]));

    float sum = 0.0f;
#pragma unroll
    for (int i = 0; i < 16; i++) { v[i] = __expf(v[i] - mx); sum += v[i]; }
#pragma unroll
    for (int off = 32; off; off >>= 1) sum += __shfl_down(sum, off);
    __syncthreads();
    if (lane == 0) red[wave] = sum;
    __syncthreads();
    const float inv = 1.0f / (red[0] + red[1] + red[2] + red[3]);

#pragma unroll
    for (int i = 0; i < 16; i++) sh[i] = f2bf(v[i] * inv);
    *(int4*)(p + base)     = *(const int4*)(sh);
    *(int4*)(p + base + 8) = *(const int4*)(sh + 8);
}

// 64x64 LDS-tiled transpose: vt[d][n] = qkv[n*3072 + 2048 + d]
__global__ __launch_bounds__(256)
void transpose_v(const short* __restrict__ qkv, short* __restrict__ vt)
{
    __shared__ short sh[64][72];   // +8 pad
    const int n0 = blockIdx.x * 64, d0 = blockIdx.y * 64;
    const int t = threadIdx.x;
    const int r = t >> 2, c = (t & 3) << 4;

    const short* src = qkv + (size_t)(n0 + r) * 3072 + 2048 + d0 + c;
    *(int4*)(&sh[r][c])     = *(const int4*)(src);
    *(int4*)(&sh[r][c + 8]) = *(const int4*)(src + 8);
    __syncthreads();

    short tmp[16];
#pragma unroll
    for (int j = 0; j < 16; j++) tmp[j] = sh[c + j][r];
    short* dst = vt + (size_t)(d0 + r) * 4096 + n0 + c;
    *(int4*)(dst)     = *(const int4*)(tmp);
    *(int4*)(dst + 8) = *(const int4*)(tmp + 8);
}

// out = partial0 + partial1 (fp32, vectorized)
__global__ __launch_bounds__(256)
void reduce2(const float* __restrict__ p, float* __restrict__ out, int n4)
{
    const int i = blockIdx.x * 256 + threadIdx.x;
    if (i >= n4) return;
    const float4 a = ((const float4*)p)[i];
    const float4 b = ((const float4*)(p + (size_t)4096 * 1024))[i];
    float4 o;
    o.x = a.x + b.x; o.y = a.y + b.y; o.z = a.z + b.z; o.w = a.w + b.w;
    ((float4*)out)[i] = o;
}

__global__ __launch_bounds__(256)
void cast4(const float* __restrict__ in, short* __restrict__ out, int n4)
{
    const int i = blockIdx.x * 256 + threadIdx.x;
    if (i >= n4) return;
    const float4 f = ((const float4*)in)[i];
    short4 o;
    o.x = f2bf(f.x); o.y = f2bf(f.y); o.z = f2bf(f.z); o.w = f2bf(f.w);
    ((short4*)out)[i] = o;
}

__global__ __launch_bounds__(256)
void cast_w3(const float* __restrict__ W1, const float* __restrict__ W2,
             const float* __restrict__ W3, short* __restrict__ out, int per4)
{
    const int i = blockIdx.x * 256 + threadIdx.x;
    if (i >= 3 * per4) return;
    const float* src = (i < per4) ? W1 : (i < 2 * per4 ? W2 : W3);
    const int j = (i < per4) ? i : (i < 2 * per4 ? i - per4 : i - 2 * per4);
    const float4 f = ((const float4*)src)[j];
    short4 o;
    o.x = f2bf(f.x); o.y = f2bf(f.y); o.z = f2bf(f.z); o.w = f2bf(f.w);
    ((short4*)out)[i] = o;
}

__global__ __launch_bounds__(256)
void bias_cat3(const float* __restrict__ b1, const float* __restrict__ b2,
               const float* __restrict__ b3, float* __restrict__ cat, int n)
{
    const int i = blockIdx.x * 256 + threadIdx.x;
    if (i < n) cat[i] = b1[i];
    else if (i < 2 * n) cat[i] = b2[i - n];
    else if (i < 3 * n) cat[i] = b3[i - 2 * n];
}

extern "C" void kernel_launch(void* const* d_in, const int* in_sizes, int n_in,
                              void* d_out, int out_size, void* d_ws, size_t ws_size,
                              hipStream_t stream)
{
    const float* x  = (const float*)d_in[0];
    const float* W1 = (const float*)d_in[1];
    const float* b1 = (const float*)d_in[2];
    const float* W2 = (const float*)d_in[3];
    const float* b2 = (const float*)d_in[4];
    const float* W3 = (const float*)d_in[5];
    const float* b3 = (const float*)d_in[6];
    float* out = (float*)d_out;

    const int N = 4096, D = 1024;

    // workspace (peak 78 MB):
    //   [0,8M)   xb      (dead after projections)
    //   [8,14M)  Wb      (dead after projections)
    //   bcat 12KB
    //   [~14,38M) qkv    (dead after transpose + S-gemm)
    //   [38,46M) vt
    //   [46,78M) S / P
    //   outp = [0,32M) fp32 partials — overlays xb/Wb/qkv, all dead by then
    short* xb   = (short*)d_ws;
    short* Wb   = xb + (size_t)N * D;
    float* bcat = (float*)(Wb + (size_t)3 * D * D);
    short* qkv  = (short*)(bcat + 3 * D);
    short* vt   = qkv + (size_t)N * 3 * D;
    short* S    = vt + (size_t)N * D;
    float* outp = (float*)d_ws;

    // 1) casts
    cast4<<<(N * D / 4) / 256, 256, 0, stream>>>(x, xb, N * D / 4);
    cast_w3<<<(3 * D * D / 4) / 256, 256, 0, stream>>>(W1, W2, W3, Wb, D * D / 4);
    bias_cat3<<<(3 * D + 255) / 256, 256, 0, stream>>>(b1, b2, b3, bcat, D);

    // 2) qkv = x @ [W1;W2;W3]^T + bias   grid (24,32)=768 blocks (3/CU)
    dim3 gqkv(3 * D / 128, N / 128);
    gemm_bt<128, 128><<<gqkv, 256, 0, stream>>>(xb, D, Wb, D, bcat, 1,
                                                qkv, 3 * D, 0, 1.0f, D, 0);

    // 3) vt[d][n] = v[n][d]   grid (64,16)=1024 blocks
    dim3 gt(N / 64, D / 64);
    transpose_v<<<gt, 256, 0, stream>>>(qkv, vt);

    // 4) S = (k q^T)/32 -> bf16   grid (32,32)=1024 blocks (4/CU)
    dim3 gs(N / 128, N / 128);
    gemm_bt<128, 128><<<gs, 256, 0, stream>>>(qkv + D, 3 * D, qkv, 3 * D,
                                              nullptr, 0, S, N, 0, 0.03125f,
                                              D, 0);

    // 5) softmax rows, in place (bf16, dense ld=4096)
    softmax_rows_bf16<<<N, 256, 0, stream>>>(S);

    // 6) out partials: split-K=2  grid (16,32,2)=1024 blocks (4/CU)
    dim3 go(D / 64, N / 128, 2);
    gemm_bt<128, 64><<<go, 256, 0, stream>>>(S, N, vt, N, nullptr, 0,
                                             outp, D, 1, 1.0f, N / 2,
                                             (size_t)N * D);

    // 7) out = partial0 + partial1
    reduce2<<<(N * D / 4) / 256, 256, 0, stream>>>(outp, out, N * D / 4);
}